// Round 17
// baseline (146.355 us; speedup 1.0000x reference)
//
#include <hip/hip_runtime.h>

#define T_DIM 720
#define B_DIM 50000

#define OFF_SEAS (T_DIM * B_DIM)                  /* 36,000,000 */
#define OFF_MSLD (OFF_SEAS + 727 * B_DIM)         /* 72,350,000 */
#define N_MSLD 718

#define NPAIR 25000
#define NBLK 391                                  /* ceil(25000/64) 1-wave blocks */
#define NW NBLK
#define LN2_SQ 0.4804530139182014f                /* (ln 2)^2 */

typedef float v2f __attribute__((ext_vector_type(2)));

// Wave64 sum via DPP: row_shr 1/2/4/8, row_bcast 15/31. Result in lane 63.
__device__ __forceinline__ float dpp_sum64(float v) {
#define DPP_ADD_STAGE(CTRL, RMASK)                                             \
  v += __int_as_float(__builtin_amdgcn_update_dpp(0, __float_as_int(v),        \
                                                  CTRL, RMASK, 0xf, false));
  DPP_ADD_STAGE(0x111, 0xf)
  DPP_ADD_STAGE(0x112, 0xf)
  DPP_ADD_STAGE(0x114, 0xf)
  DPP_ADD_STAGE(0x118, 0xf)
  DPP_ADD_STAGE(0x142, 0xa)
  DPP_ADD_STAGE(0x143, 0xc)
#undef DPP_ADD_STAGE
  return v;
}

__device__ __forceinline__ v2f v2div(v2f a, v2f b) {
  v2f r;
  r.x = __fdividef(a.x, b.x);
  r.y = __fdividef(a.y, b.y);
  return r;
}
__device__ __forceinline__ v2f v2log2(v2f a) {
  v2f r;
  r.x = __log2f(a.x);
  r.y = __log2f(a.y);
  return r;
}

#define PIN7(QB)                                                               \
  asm volatile("" : "+v"(QB[0]), "+v"(QB[1]), "+v"(QB[2]), "+v"(QB[3]),        \
                    "+v"(QB[4]), "+v"(QB[5]), "+v"(QB[6]));

// NT v2f loads (512 B/wave-instr) for group G (rows 1+7G..7+7G, clamped).
#define PREFETCH(QB, G)                                                        \
  {                                                                            \
    int tp = 1 + 7 * (G);                                                      \
    _Pragma("unroll") for (int j = 0; j < 7; ++j) {                            \
      int r = tp + j;                                                          \
      r = r > 719 ? 719 : r;                                                   \
      QB[j] = __builtin_nontemporal_load(                                      \
          (const v2f*)((const char*)train + (size_t)r * B_DIM * 4 +            \
                       8ull * (unsigned)pc));                                  \
    }                                                                          \
  }

// One group, batched ILP phases, two independent series chains per thread.
#define ESRNN_GROUP_N(QB, NS)                                                  \
  {                                                                            \
    v2f xds[7], nlv[7], llv[7];                                                \
    _Pragma("unroll") for (int j = 0; j < (NS); ++j)                           \
        xds[j] = v2div(QB[j], buf[j]);                                         \
    nlv[0] = lsm2 * xds[0] + olm2 * lev;                                       \
    _Pragma("unroll") for (int j = 1; j < (NS); ++j)                           \
        nlv[j] = lsm2 * xds[j] + olm2 * nlv[j - 1];                            \
    _Pragma("unroll") for (int j = 0; j < (NS); ++j)                           \
        llv[j] = v2log2(nlv[j]);                                               \
    _Pragma("unroll") for (int j = 0; j < (NS); ++j)                           \
        buf[j] = ssm2 * v2div(QB[j], nlv[j]) + osm2 * buf[j];                  \
    if (valid) {                                                               \
      _Pragma("unroll") for (int j = 0; j < (NS); ++j) {                       \
        *(v2f*)(lbase + boff + (unsigned)(j * B_DIM * 4)) = nlv[j];            \
        *(v2f*)(sbase + boff + (unsigned)(j * B_DIM * 4)) = buf[j];            \
      }                                                                        \
    }                                                                          \
    boff += (NS)*B_DIM * 4;                                                    \
    float sqv[7];                                                              \
    {                                                                          \
      v2f ld0 = llv[0] - llev;                                                 \
      v2f d0 = ld0 - pld;                                                      \
      sqv[0] = valid ? (d0.x * d0.x + d0.y * d0.y) : 0.0f;                     \
      v2f ldp = ld0;                                                           \
      _Pragma("unroll") for (int j = 1; j < (NS); ++j) {                       \
        v2f ld = llv[j] - llv[j - 1];                                          \
        v2f d = ld - ldp;                                                      \
        sqv[j] = valid ? (d.x * d.x + d.y * d.y) : 0.0f;                       \
        ldp = ld;                                                              \
      }                                                                        \
      pld = ldp;                                                               \
    }                                                                          \
    llev = llv[(NS)-1];                                                        \
    lev = nlv[(NS)-1];                                                         \
    _Pragma("unroll") for (int j = 0; j < (NS); ++j)                           \
        sqv[j] = dpp_sum64(sqv[j]);                                            \
    if (lane == 63) {                                                          \
      int tb = 1 + 7 * g;                                                      \
      _Pragma("unroll") for (int j = 0; j < (NS); ++j)                         \
          lds_p[tb + j - 1] = sqv[j];                                          \
    }                                                                          \
  }

// Body(g): issue loads for g+3; pin buffer issued 2 bodies ago; consume QB.
#define ESRNN_GROUP(QB, QPIN, QLD)                                             \
  {                                                                            \
    PREFETCH(QLD, g + 3)                                                       \
    PIN7(QPIN)                                                                 \
    ESRNN_GROUP_N(QB, 7)                                                       \
    ++g;                                                                       \
  }

__global__ __launch_bounds__(64) void esrnn_main(
    const float* __restrict__ train,        // (720, B)
    const float* __restrict__ lev_sms,      // (B,)
    const float* __restrict__ seas_sms,     // (B,)
    const float* __restrict__ init_seas_in, // (B, 7)
    float* __restrict__ levs_out,           // (720, B)
    float* __restrict__ seas_out,           // (727, B)
    float* __restrict__ partial)            // (NW, 718) wave-major partials
{
  __shared__ float lds_p[720];  // slot r+1 holds row r; slot 0 = dummy (t<2)

  int lane = threadIdx.x;
  int wid = blockIdx.x;
  int p = wid * 64 + lane;  // pair index: series 2p, 2p+1
  bool valid = (p < NPAIR);
  int pc = valid ? p : (NPAIR - 1);

  v2f lraw = *(const v2f*)&lev_sms[2 * pc];
  v2f sraw = *(const v2f*)&seas_sms[2 * pc];
  v2f lsm2, ssm2;
  lsm2.x = 1.0f / (1.0f + __expf(-lraw.x));
  lsm2.y = 1.0f / (1.0f + __expf(-lraw.y));
  ssm2.x = 1.0f / (1.0f + __expf(-sraw.x));
  ssm2.y = 1.0f / (1.0f + __expf(-sraw.y));
  v2f olm2 = 1.0f - lsm2;
  v2f osm2 = 1.0f - ssm2;

  v2f isv[7];
#pragma unroll
  for (int j = 0; j < 7; ++j) {
    isv[j].x = __expf(init_seas_in[pc * 14 + j]);
    isv[j].y = __expf(init_seas_in[pc * 14 + 7 + j]);
  }

  v2f x0 = *(const v2f*)((const char*)train + 8ull * (unsigned)pc);
  v2f lev = v2div(x0, isv[0]);

  if (valid) {
    *(v2f*)&levs_out[2 * p] = lev;
#pragma unroll
    for (int j = 0; j < 7; ++j)
      *(v2f*)((char*)seas_out + (size_t)j * B_DIM * 4 + 8ull * (unsigned)p) =
          isv[j];
    *(v2f*)((char*)seas_out + (size_t)7 * B_DIM * 4 + 8ull * (unsigned)p) =
        isv[0];
  }

  v2f buf[7];
#pragma unroll
  for (int j = 0; j < 6; ++j) buf[j] = isv[j + 1];
  buf[6] = isv[0];

  v2f llev = v2log2(lev);  // log2 units; ln2^2 applied in reduce kernel
  v2f pld;
  pld.x = 0.0f;
  pld.y = 0.0f;

  char* lbase = (char*)levs_out + (size_t)B_DIM * 4;      // row t=1
  char* sbase = (char*)seas_out + (size_t)8 * B_DIM * 4;  // row t+7=8
  unsigned boff = 8u * (unsigned)p;

  v2f xa[7], xb[7], xc[7], xd[7];
  int g = 0;
  PREFETCH(xa, 0)
  PREFETCH(xb, 1)
  PREFETCH(xc, 2)

  // 100 groups = 25 x 4-buffer rotation, prefetch distance 3.
  for (int k = 0; k < 25; ++k) {
    ESRNN_GROUP(xa, xb, xd)
    ESRNN_GROUP(xb, xc, xa)
    ESRNN_GROUP(xc, xd, xb)
    ESRNN_GROUP(xd, xa, xc)
  }
  // groups 100, 101
  ESRNN_GROUP(xa, xb, xd)
  ESRNN_GROUP(xb, xc, xa)

  // tail: t = 715..719 = group 102 in xc, buf pos 0..4
  ESRNN_GROUP_N(xc, 5)

  // Flush this wave's 718 row-partials to its contiguous private strip.
  __syncthreads();  // single-wave block: drains LDS writes
  float* mystrip = partial + (size_t)wid * N_MSLD;
  for (int i = lane; i < N_MSLD; i += 64) mystrip[i] = lds_p[i + 1];
}

__global__ __launch_bounds__(64) void esrnn_reduce2(
    const float* __restrict__ partial, float* __restrict__ msld) {
  int row = blockIdx.x;  // 0..717
  int lane = threadIdx.x;
  float s = 0.0f;
  for (int i = lane; i < NW; i += 64) s += partial[(size_t)i * N_MSLD + row];
  float tot = dpp_sum64(s);
  if (lane == 63) msld[row] = tot * (LN2_SQ / (float)B_DIM);
}

extern "C" void kernel_launch(void* const* d_in, const int* in_sizes, int n_in,
                              void* d_out, int out_size, void* d_ws,
                              size_t ws_size, hipStream_t stream) {
  const float* train = (const float*)d_in[0];
  const float* lev_sms = (const float*)d_in[1];
  const float* seas_sms = (const float*)d_in[2];
  const float* init_seas = (const float*)d_in[3];

  float* out = (float*)d_out;
  float* levs = out;
  float* seas = out + OFF_SEAS;
  float* msld = out + OFF_MSLD;
  float* partial = (float*)d_ws;  // NW*718*4 ~= 1.12 MB, wave-major

  esrnn_main<<<NBLK, 64, 0, stream>>>(train, lev_sms, seas_sms, init_seas,
                                      levs, seas, partial);
  esrnn_reduce2<<<N_MSLD, 64, 0, stream>>>(partial, msld);
}

// Round 18
// 116.879 us; speedup vs baseline: 1.2522x; 1.2522x over previous
//
#include <hip/hip_runtime.h>

#define T_DIM 720
#define B_DIM 50000

#define OFF_SEAS (T_DIM * B_DIM)                  /* 36,000,000 */
#define SEAS_ROWS 727
#define OFF_MSLD (OFF_SEAS + SEAS_ROWS * B_DIM)   /* 72,350,000 */
#define N_MSLD 718

#define NBLK 782                                  /* ceil(50000/64) 1-wave blocks */
#define NW NBLK
#define LN2_SQ 0.4804530139182014f                /* (ln 2)^2 */

// Wave64 sum via DPP: row_shr 1/2/4/8, row_bcast 15/31. Result in lane 63.
__device__ __forceinline__ float dpp_sum64(float v) {
#define DPP_ADD_STAGE(CTRL, RMASK)                                             \
  v += __int_as_float(__builtin_amdgcn_update_dpp(0, __float_as_int(v),        \
                                                  CTRL, RMASK, 0xf, false));
  DPP_ADD_STAGE(0x111, 0xf)  // row_shr:1
  DPP_ADD_STAGE(0x112, 0xf)  // row_shr:2
  DPP_ADD_STAGE(0x114, 0xf)  // row_shr:4
  DPP_ADD_STAGE(0x118, 0xf)  // row_shr:8
  DPP_ADD_STAGE(0x142, 0xa)  // row_bcast:15
  DPP_ADD_STAGE(0x143, 0xc)  // row_bcast:31
#undef DPP_ADD_STAGE
  return v;
}

// Issue loads for group G (rows 1+7G .. 7+7G, clamped) into QB. No pin here.
#define PREFETCH(QB, G)                                                        \
  {                                                                            \
    int tp = 1 + 7 * (G);                                                      \
    _Pragma("unroll") for (int j = 0; j < 7; ++j) {                            \
      int r = tp + j;                                                          \
      r = r > 719 ? 719 : r;                                                   \
      QB[j] = __builtin_nontemporal_load(&train[r * B_DIM + bc]);              \
    }                                                                          \
  }

// Zero-cost register pin: forces QB's loads to be materialized here (two
// group-times after issue, one body before use) — keeps prefetch distance
// real without early vmcnt drains.
#define PIN7(QB)                                                               \
  asm volatile("" : "+v"(QB[0]), "+v"(QB[1]), "+v"(QB[2]), "+v"(QB[3]),        \
                    "+v"(QB[4]), "+v"(QB[5]), "+v"(QB[6]));

// One group, batched ILP phases (R9/R12 structure). Per-wave partials to LDS.
#define ESRNN_GROUP_N(QB, NS)                                                  \
  {                                                                            \
    float xds[7], nlv[7], llv[7];                                              \
    _Pragma("unroll") for (int j = 0; j < (NS); ++j)                           \
        xds[j] = __fdividef(QB[j], buf[j]);                                    \
    nlv[0] = fmaf(lsm, xds[0], olm * lev);                                     \
    _Pragma("unroll") for (int j = 1; j < (NS); ++j)                           \
        nlv[j] = fmaf(lsm, xds[j], olm * nlv[j - 1]);                          \
    _Pragma("unroll") for (int j = 0; j < (NS); ++j)                           \
        llv[j] = __log2f(nlv[j]);                                              \
    _Pragma("unroll") for (int j = 0; j < (NS); ++j)                           \
        buf[j] = fmaf(ssm, __fdividef(QB[j], nlv[j]), osm * buf[j]);           \
    if (valid) {                                                               \
      _Pragma("unroll") for (int j = 0; j < (NS); ++j) {                       \
        *(float*)(lbase + boff + (unsigned)(j * B_DIM * 4)) = nlv[j];          \
        *(float*)(sbase + boff + (unsigned)(j * B_DIM * 4)) = buf[j];          \
      }                                                                        \
    }                                                                          \
    boff += (NS)*B_DIM * 4;                                                    \
    float sqv[7];                                                              \
    {                                                                          \
      float ld0 = llv[0] - llev;                                               \
      float d0 = ld0 - pld;                                                    \
      sqv[0] = valid ? d0 * d0 : 0.0f;                                         \
      float ldp = ld0;                                                         \
      _Pragma("unroll") for (int j = 1; j < (NS); ++j) {                       \
        float ld = llv[j] - llv[j - 1];                                        \
        float d = ld - ldp;                                                    \
        sqv[j] = valid ? d * d : 0.0f;                                         \
        ldp = ld;                                                              \
      }                                                                        \
      pld = ldp;                                                               \
    }                                                                          \
    llev = llv[(NS)-1];                                                        \
    lev = nlv[(NS)-1];                                                         \
    _Pragma("unroll") for (int j = 0; j < (NS); ++j)                           \
        sqv[j] = dpp_sum64(sqv[j]);                                            \
    if (lane == 63) {                                                          \
      int tb = 1 + 7 * g;                                                      \
      _Pragma("unroll") for (int j = 0; j < (NS); ++j)                         \
          lds_p[tb + j - 1] = sqv[j];                                          \
    }                                                                          \
  }

// Body(g): issue loads for group g+3 into QLD; pin QPIN (issued at body g-2,
// consumed at body g+1); consume QB (issued at body g-3, pinned at body g-1).
#define ESRNN_GROUP(QB, QPIN, QLD)                                             \
  {                                                                            \
    PREFETCH(QLD, g + 3)                                                       \
    PIN7(QPIN)                                                                 \
    ESRNN_GROUP_N(QB, 7)                                                       \
    ++g;                                                                       \
  }

__global__ __launch_bounds__(64) void esrnn_main(
    const float* __restrict__ train,        // (720, B)
    const float* __restrict__ lev_sms,      // (B,)
    const float* __restrict__ seas_sms,     // (B,)
    const float* __restrict__ init_seas_in, // (B, 7)
    float* __restrict__ levs_out,           // (720, B)
    float* __restrict__ seas_out,           // (727, B)
    float* __restrict__ partial)            // (NW, 718) wave-major partials
{
  __shared__ float lds_p[720];  // slot r+1 holds row r; slot 0 = dummy (t<2)

  int b = blockIdx.x * 64 + threadIdx.x;
  bool valid = (b < B_DIM);
  int bc = valid ? b : (B_DIM - 1);
  int lane = threadIdx.x;
  int wid = blockIdx.x;

  float lsm = 1.0f / (1.0f + __expf(-lev_sms[bc]));
  float ssm = 1.0f / (1.0f + __expf(-seas_sms[bc]));
  float olm = 1.0f - lsm;
  float osm = 1.0f - ssm;

  float is[7];
#pragma unroll
  for (int j = 0; j < 7; ++j) is[j] = __expf(init_seas_in[bc * 7 + j]);

  float seas0 = is[0];
  float x0 = train[bc];
  float lev = __fdividef(x0, seas0);

  if (valid) {
    levs_out[b] = lev;
#pragma unroll
    for (int j = 0; j < 7; ++j) seas_out[j * B_DIM + b] = is[j];
    seas_out[7 * B_DIM + b] = seas0;
  }

  float buf[7];
#pragma unroll
  for (int j = 0; j < 6; ++j) buf[j] = is[j + 1];
  buf[6] = seas0;

  float llev = __log2f(lev);  // log2 units; ln2^2 applied in reduce kernel
  float pld = 0.0f;

  // saddr-form store bases + shared per-lane byte offset.
  char* lbase = (char*)levs_out + (size_t)B_DIM * 4;      // row t=1
  char* sbase = (char*)seas_out + (size_t)8 * B_DIM * 4;  // row t+7=8
  unsigned int boff = (unsigned int)b * 4u;

  float xa[7], xb[7], xc[7], xd[7];
  int g = 0;
  PREFETCH(xa, 0)
  PREFETCH(xb, 1)
  PREFETCH(xc, 2)

  // 100 groups = 25 x 4-buffer rotation, prefetch distance 3.
  // Each buffer: issued at body g, pinned at body g+2, consumed at body g+3.
  for (int k = 0; k < 25; ++k) {
    ESRNN_GROUP(xa, xb, xd)
    ESRNN_GROUP(xb, xc, xa)
    ESRNN_GROUP(xc, xd, xb)
    ESRNN_GROUP(xd, xa, xc)
  }
  // groups 100, 101 (their prefetches clamp to row 719; harmless)
  ESRNN_GROUP(xa, xb, xd)
  ESRNN_GROUP(xb, xc, xa)

  // tail: t = 715..719 = group 102 in xc (pinned during body 101), buf 0..4
  ESRNN_GROUP_N(xc, 5)

  // Flush this wave's 718 row-partials to its contiguous private strip.
  __syncthreads();  // single-wave block: just drains LDS writes
  float* mystrip = partial + (size_t)wid * N_MSLD;
  for (int i = lane; i < N_MSLD; i += 64) mystrip[i] = lds_p[i + 1];
}

__global__ __launch_bounds__(64) void esrnn_reduce2(
    const float* __restrict__ partial, float* __restrict__ msld) {
  int row = blockIdx.x;  // 0..717
  int lane = threadIdx.x;
  float s = 0.0f;
  for (int i = lane; i < NW; i += 64)
    s += partial[(size_t)i * N_MSLD + row];
  float tot = dpp_sum64(s);
  if (lane == 63) msld[row] = tot * (LN2_SQ / (float)B_DIM);
}

extern "C" void kernel_launch(void* const* d_in, const int* in_sizes, int n_in,
                              void* d_out, int out_size, void* d_ws,
                              size_t ws_size, hipStream_t stream) {
  const float* train = (const float*)d_in[0];
  const float* lev_sms = (const float*)d_in[1];
  const float* seas_sms = (const float*)d_in[2];
  const float* init_seas = (const float*)d_in[3];

  float* out = (float*)d_out;
  float* levs = out;
  float* seas = out + OFF_SEAS;
  float* msld = out + OFF_MSLD;
  float* partial = (float*)d_ws;  // NW*718*4 ~= 2.25 MB, wave-major

  esrnn_main<<<NBLK, 64, 0, stream>>>(train, lev_sms, seas_sms, init_seas,
                                      levs, seas, partial);
  esrnn_reduce2<<<N_MSLD, 64, 0, stream>>>(partial, msld);
}